// Round 6
// baseline (368.798 us; speedup 1.0000x reference)
//
#include <hip/hip_runtime.h>
#include <cstdint>
#include <cstddef>

#define B_   2
#define S_   2048
#define H_   2048
#define NH_  16
#define HD_  128
#define MM_  (B_ * S_)          /* 4096 rows of x */
#define K_   H_                 /* 2048 reduction dim for projections */
#define SCALE_F 0.08838834764831845f
#define LOG2E_F 1.4426950408889634f
#define QSCALE_F (SCALE_F * LOG2E_F)

typedef __bf16 bf16_t;
typedef __attribute__((ext_vector_type(8))) __bf16 bf16x8;
typedef __attribute__((ext_vector_type(4))) float  f32x4;
typedef __attribute__((ext_vector_type(4))) float  floatx4;

static __device__ __forceinline__ f32x4 mfma_16x16x32(bf16x8 a, bf16x8 b, f32x4 c) {
  return __builtin_amdgcn_mfma_f32_16x16x32_bf16(a, b, c, 0, 0, 0);
}

static __device__ __forceinline__ void gl2lds16(const bf16_t* g, bf16_t* l) {
  __builtin_amdgcn_global_load_lds(
      (const __attribute__((address_space(1))) void*)g,
      (__attribute__((address_space(3))) void*)l, 16, 0, 0);
}

static __device__ __forceinline__ float exp2_hw(float x) {
  float r;
  asm("v_exp_f32 %0, %1" : "=v"(r) : "v"(x));
  return r;
}

// ---------------------------------------------------------------- fp32->bf16
__global__ void cvt_f32_bf16(const float* __restrict__ in, bf16_t* __restrict__ out, int n8) {
  int i = blockIdx.x * blockDim.x + threadIdx.x;
  const int stride = gridDim.x * blockDim.x;
  for (; i < n8; i += stride) {
    const floatx4* p = (const floatx4*)(in + (size_t)i * 8);
    floatx4 a = p[0], b = p[1];
    bf16x8 o;
    o[0] = (bf16_t)a.x; o[1] = (bf16_t)a.y; o[2] = (bf16_t)a.z; o[3] = (bf16_t)a.w;
    o[4] = (bf16_t)b.x; o[5] = (bf16_t)b.y; o[6] = (bf16_t)b.z; o[7] = (bf16_t)b.w;
    *(bf16x8*)(out + (size_t)i * 8) = o;
  }
}

__global__ void cvt4_f32_bf16(const float* __restrict__ i0, const float* __restrict__ i1,
                              const float* __restrict__ i2, const float* __restrict__ i3,
                              bf16_t* o0, bf16_t* o1, bf16_t* o2, bf16_t* o3, int n8) {
  const float* in = (blockIdx.y == 0) ? i0 : (blockIdx.y == 1) ? i1 : (blockIdx.y == 2) ? i2 : i3;
  bf16_t*      out = (blockIdx.y == 0) ? o0 : (blockIdx.y == 1) ? o1 : (blockIdx.y == 2) ? o2 : o3;
  int i = blockIdx.x * blockDim.x + threadIdx.x;
  const int stride = gridDim.x * blockDim.x;
  for (; i < n8; i += stride) {
    const floatx4* p = (const floatx4*)(in + (size_t)i * 8);
    floatx4 a = p[0], b = p[1];
    bf16x8 o;
    o[0] = (bf16_t)a.x; o[1] = (bf16_t)a.y; o[2] = (bf16_t)a.z; o[3] = (bf16_t)a.w;
    o[4] = (bf16_t)b.x; o[5] = (bf16_t)b.y; o[6] = (bf16_t)b.z; o[7] = (bf16_t)b.w;
    *(bf16x8*)(out + (size_t)i * 8) = o;
  }
}

// ----------------------------------------------- 256x256x64 8-wave GEMM, T2+T4+T5
// C = A * B^T + bias. A:[M,K] bf16 rm. B:[N,K] bf16 rm (pre-transposed weights).
// 512 thr = 8 waves (2M x 4N), per-wave C = 128x64. LDS 128KB (dbuf A+B tiles,
// [256][64] linear layout; ds_read chunk-XOR swizzle, inverse-swizzled global
// source). 2-tiles-ahead prefetch, counted vmcnt(8) per K-tile, raw s_barrier.
// MODE 0: fused QKV (grid.x = 16*24; nc>>3 selects W/bias/dst).
//   Q/K out: frag-major [bh][s>>4][d>>5][(s&15)|(((d>>3)&3)<<4)][d&7], Q pre-scaled.
//   V   out: frag-major [bh][s>>6][d>>4][(s>>5)&1][(d&15)|(((s>>3)&3)<<4)][s&7].
// MODE 1: O-projection (grid.x = 16*8), fp32 [M,H] + bias.
template <int MODE>
__global__ __launch_bounds__(512, 2) void gemm8p(
    const bf16_t* __restrict__ A,
    const bf16_t* __restrict__ W0, const bf16_t* __restrict__ W1, const bf16_t* __restrict__ W2,
    const float* __restrict__ bias0, const float* __restrict__ bias1, const float* __restrict__ bias2,
    bf16_t* __restrict__ dq, bf16_t* __restrict__ dk, bf16_t* __restrict__ dv,
    float* __restrict__ outf)
{
  __shared__ __align__(16) bf16_t Albuf[2][256 * 64];   // 64 KB
  __shared__ __align__(16) bf16_t Blbuf[2][256 * 64];   // 64 KB

  const int tt   = threadIdx.x;
  const int lane = tt & 63;
  const int wid  = tt >> 6;
  const int wm   = wid >> 2;   // 0..1
  const int wn   = wid & 3;    // 0..3

  // XCD-chunked swizzle on linear grid (nwg % 8 == 0 for both modes)
  int lin = blockIdx.x;
  const int cpx = gridDim.x >> 3;
  lin = (lin & 7) * cpx + (lin >> 3);
  const int tm = lin & 15;        // M tile 0..15
  const int nc = lin >> 4;        // N tile (24 for MODE0, 8 for MODE1)
  const int bm = tm * 256;

  int wsel = 0, bnl;
  const bf16_t* Bw;
  const float*  bias;
  bf16_t* dsth = nullptr;
  if constexpr (MODE == 0) {
    wsel = nc >> 3;
    bnl  = (nc & 7) * 256;
    Bw   = (wsel == 0) ? W0 : ((wsel == 1) ? W1 : W2);
    bias = (wsel == 0) ? bias0 : ((wsel == 1) ? bias1 : bias2);
    dsth = (wsel == 0) ? dq : ((wsel == 1) ? dk : dv);
  } else {
    bnl = nc * 256;
    Bw = W0; bias = bias0;
  }

  // stage K-tile t into buf b: 8 gl2lds/thread (4 A + 4 B), linear LDS dest,
  // inverse-swizzled global column chunk g = (c&7) ^ (row&7).
  auto stage = [&](int t, int b) {
    const int kb = t * 64;
    #pragma unroll
    for (int j = 0; j < 4; ++j) {
      const int cl = tt + j * 512;            // 16B-chunk id 0..2047
      const int R  = cl >> 3;                 // tile row 0..255
      const int g  = (cl & 7) ^ (R & 7);      // source column chunk
      const int cb = (wid * 64 + j * 512) * 8;  // wave-uniform LDS elem base
      gl2lds16(A  + (size_t)(bm  + R) * K_ + kb + g * 8, &Albuf[b][cb]);
      gl2lds16(Bw + (size_t)(bnl + R) * K_ + kb + g * 8, &Blbuf[b][cb]);
    }
  };

  f32x4 acc[8][4] = {};

  stage(0, 0);
  stage(1, 1);

  const int NTK = K_ / 64;   // 32
  #pragma unroll 1
  for (int t = 0; t < NTK; ++t) {
    const int b = t & 1;
    // tile t's 8 loads complete; tile t+1's 8 may stay in flight (T4)
    if (t + 1 < NTK) asm volatile("s_waitcnt vmcnt(8)" ::: "memory");
    else             asm volatile("s_waitcnt vmcnt(0)" ::: "memory");
    __builtin_amdgcn_s_barrier();
    __builtin_amdgcn_sched_barrier(0);

    const bf16_t* Al = &Albuf[b][0];
    const bf16_t* Bl = &Blbuf[b][0];

    #pragma unroll
    for (int qm = 0; qm < 2; ++qm) {
      bf16x8 af[4][2];
      #pragma unroll
      for (int m = 0; m < 4; ++m)
        #pragma unroll
        for (int kk = 0; kk < 2; ++kk) {
          const int R = wm * 128 + qm * 64 + m * 16 + (lane & 15);
          const int c = (kk * 4 + (lane >> 4)) ^ (R & 7);
          af[m][kk] = *(const bf16x8*)&Al[R * 64 + c * 8];
        }
      #pragma unroll
      for (int qn = 0; qn < 2; ++qn) {
        bf16x8 bfv[2][2];
        #pragma unroll
        for (int n = 0; n < 2; ++n)
          #pragma unroll
          for (int kk = 0; kk < 2; ++kk) {
            const int Rb = wn * 64 + qn * 32 + n * 16 + (lane & 15);
            const int c  = (kk * 4 + (lane >> 4)) ^ (Rb & 7);
            bfv[n][kk] = *(const bf16x8*)&Bl[Rb * 64 + c * 8];
          }
        __builtin_amdgcn_s_setprio(1);
        #pragma unroll
        for (int kk = 0; kk < 2; ++kk)      // kk outer: 8 indep MFMAs between reuse
          #pragma unroll
          for (int m = 0; m < 4; ++m)
            #pragma unroll
            for (int n = 0; n < 2; ++n)
              acc[qm * 4 + m][qn * 2 + n] =
                  mfma_16x16x32(af[m][kk], bfv[n][kk], acc[qm * 4 + m][qn * 2 + n]);
        __builtin_amdgcn_s_setprio(0);
      }
    }

    __builtin_amdgcn_sched_barrier(0);
    __builtin_amdgcn_s_barrier();          // all waves done reading buf b
    if (t + 2 < NTK) stage(t + 2, b);      // refill freed buffer
  }

  // epilogue. C/D frag: col = lane&15, row = (lane>>4)*4 + r
  #pragma unroll
  for (int bj = 0; bj < 4; ++bj) {
    const int col = bnl + wn * 64 + bj * 16 + (lane & 15);
    const float bv = bias[col];
    #pragma unroll
    for (int ai = 0; ai < 8; ++ai) {
      #pragma unroll
      for (int r = 0; r < 4; ++r) {
        const int row = bm + wm * 128 + ai * 16 + (lane >> 4) * 4 + r;
        float v = acc[ai][bj][r] + bv;
        if constexpr (MODE == 0) {
          const int ss = row & (S_ - 1);
          const int dd = col & (HD_ - 1);
          const size_t bh = (size_t)((row >> 11) * NH_ + (col >> 7));
          if (wsel == 0) v *= QSCALE_F;
          size_t idx;
          if (wsel == 2) {
            const size_t t1 = bh * 32 + (ss >> 6);
            const size_t t2 = t1 * 8 + (dd >> 4);
            const size_t t3 = t2 * 2 + ((ss >> 5) & 1);
            const size_t ln = (size_t)((dd & 15) | (((ss >> 3) & 3) << 4));
            idx = (t3 * 64 + ln) * 8 + (size_t)(ss & 7);
          } else {
            const size_t t1 = bh * 128 + (ss >> 4);
            const size_t t2 = t1 * 4 + (dd >> 5);
            const size_t ln = (size_t)((ss & 15) | (((dd >> 3) & 3) << 4));
            idx = (t2 * 64 + ln) * 8 + (size_t)(dd & 7);
          }
          dsth[idx] = (bf16_t)v;
        } else {
          outf[(size_t)row * H_ + col] = v;
        }
      }
    }
  }
}

// ------------------------------------------------------------ flash attention
// (unchanged from round 5 — verified) 512 blocks XCD-swizzled, 4 waves x 32
// q-rows, KV tile 64, frag-major K/V staged via linear global_load_lds.
#define KVB 64
#define NT_ (S_ / KVB)
#define TILE_E 8192

__global__ __launch_bounds__(256, 2) void attn_kernel(
    const bf16_t* __restrict__ Qf, const bf16_t* __restrict__ Kf,
    const bf16_t* __restrict__ Vf, const float* __restrict__ mask,
    bf16_t* __restrict__ ctx)
{
  __shared__ __align__(16) bf16_t Klds[TILE_E];
  __shared__ __align__(16) bf16_t Vlds[TILE_E];
  __shared__ __align__(16) bf16_t Plds[4][32 * KVB];

  const int t = threadIdx.x;
  const int lane = t & 63;
  const int wid  = t >> 6;

  const int orig = blockIdx.x;
  const int wg = (orig & 7) * 64 + (orig >> 3);
  const int qt = wg & 15;
  const int bh = wg >> 4;
  const int b  = bh >> 4;
  const int h  = bh & 15;
  const int q0 = qt * 128 + wid * 32;

  const bf16_t* Kh0 = Kf + (size_t)bh * (NT_ * TILE_E);
  const bf16_t* Vh0 = Vf + (size_t)bh * (NT_ * TILE_E);
  const float*  mg  = mask + (size_t)b * S_;

  const bf16_t* Qt = Qf + (((size_t)bh * 128 + (q0 >> 4)) * 4) * 512;
  bf16x8 qf[2][4];
  #pragma unroll
  for (int mh = 0; mh < 2; ++mh)
    #pragma unroll
    for (int ks = 0; ks < 4; ++ks)
      qf[mh][ks] = *(const bf16x8*)&Qt[((mh * 4 + ks) * 64 + lane) * 8];

  f32x4 acc[2][8] = {};
  float m_run[2][4], l_run[2][4];
  #pragma unroll
  for (int mh = 0; mh < 2; ++mh)
    #pragma unroll
    for (int r = 0; r < 4; ++r) { m_run[mh][r] = -INFINITY; l_run[mh][r] = 0.0f; }

  char* Pw = (char*)&Plds[wid][0];

  #pragma unroll 1
  for (int it = 0; it < NT_; ++it) {
    {
      const bf16_t* Ksrc = Kh0 + (size_t)it * TILE_E;
      const bf16_t* Vsrc = Vh0 + (size_t)it * TILE_E;
      #pragma unroll
      for (int i = 0; i < 4; ++i) {
        const int base = (i * 256 + wid * 64) * 8;
        gl2lds16(Ksrc + base + lane * 8, &Klds[base]);
        gl2lds16(Vsrc + base + lane * 8, &Vlds[base]);
      }
    }
    __syncthreads();

    f32x4 sacc[2][4] = {};
    #pragma unroll
    for (int ns = 0; ns < 4; ++ns) {
      #pragma unroll
      for (int ks = 0; ks < 4; ++ks) {
        const bf16x8 kf = *(const bf16x8*)&Klds[((ns * 4 + ks) * 64 + lane) * 8];
        __builtin_amdgcn_s_setprio(1);
        sacc[0][ns] = mfma_16x16x32(qf[0][ks], kf, sacc[0][ns]);
        sacc[1][ns] = mfma_16x16x32(qf[1][ks], kf, sacc[1][ns]);
        __builtin_amdgcn_s_setprio(0);
      }
    }

    const int kv0 = it * KVB;
    float msk[4];
    #pragma unroll
    for (int ns = 0; ns < 4; ++ns)
      msk[ns] = mg[kv0 + ns * 16 + (lane & 15)] * LOG2E_F;

    float sv[2][4][4], tmax[2][4];
    #pragma unroll
    for (int mh = 0; mh < 2; ++mh) {
      #pragma unroll
      for (int r = 0; r < 4; ++r) tmax[mh][r] = -INFINITY;
      #pragma unroll
      for (int ns = 0; ns < 4; ++ns)
        #pragma unroll
        for (int r = 0; r < 4; ++r) {
          sv[mh][ns][r] = sacc[mh][ns][r] + msk[ns];
          tmax[mh][r] = fmaxf(tmax[mh][r], sv[mh][ns][r]);
        }
      #pragma unroll
      for (int off = 1; off < 16; off <<= 1)
        #pragma unroll
        for (int r = 0; r < 4; ++r)
          tmax[mh][r] = fmaxf(tmax[mh][r], __shfl_xor(tmax[mh][r], off));
    }

    bool small = true;
    #pragma unroll
    for (int mh = 0; mh < 2; ++mh)
      #pragma unroll
      for (int r = 0; r < 4; ++r)
        small = small && (tmax[mh][r] <= m_run[mh][r] + 8.0f);
    if (!__all(small)) {
      float scl[2][4];
      #pragma unroll
      for (int mh = 0; mh < 2; ++mh)
        #pragma unroll
        for (int r = 0; r < 4; ++r) {
          const float mnew = fmaxf(m_run[mh][r], tmax[mh][r]);
          scl[mh][r] = exp2_hw(m_run[mh][r] - mnew);
          m_run[mh][r] = mnew;
          l_run[mh][r] *= scl[mh][r];
        }
      #pragma unroll
      for (int mh = 0; mh < 2; ++mh)
        #pragma unroll
        for (int ds = 0; ds < 8; ++ds)
          #pragma unroll
          for (int r = 0; r < 4; ++r)
            acc[mh][ds][r] *= scl[mh][r];
    }

    float rsum[2][4] = {};
    #pragma unroll
    for (int mh = 0; mh < 2; ++mh)
      #pragma unroll
      for (int ns = 0; ns < 4; ++ns)
        #pragma unroll
        for (int r = 0; r < 4; ++r) {
          const float p = exp2_hw(sv[mh][ns][r] - m_run[mh][r]);
          rsum[mh][r] += p;
          const int qq = mh * 16 + (lane >> 4) * 4 + r;
          const int pb = (qq << 7) + ((((ns << 5) | ((lane & 15) << 1))) ^ ((qq & 7) << 4));
          *(bf16_t*)(Pw + pb) = (bf16_t)p;
        }

    bf16x8 pf[2][2];
    #pragma unroll
    for (int mh = 0; mh < 2; ++mh)
      #pragma unroll
      for (int k2 = 0; k2 < 2; ++k2) {
        const int qq = mh * 16 + (lane & 15);
        const int pb = (qq << 7) + (((k2 << 6) | ((lane >> 4) << 4)) ^ ((qq & 7) << 4));
        pf[mh][k2] = *(const bf16x8*)(Pw + pb);
      }

    #pragma unroll
    for (int ds = 0; ds < 8; ++ds) {
      const bf16x8 vf0 = *(const bf16x8*)&Vlds[((ds * 2 + 0) * 64 + lane) * 8];
      const bf16x8 vf1 = *(const bf16x8*)&Vlds[((ds * 2 + 1) * 64 + lane) * 8];
      __builtin_amdgcn_s_setprio(1);
      #pragma unroll
      for (int mh = 0; mh < 2; ++mh) {
        acc[mh][ds] = mfma_16x16x32(pf[mh][0], vf0, acc[mh][ds]);
        acc[mh][ds] = mfma_16x16x32(pf[mh][1], vf1, acc[mh][ds]);
      }
      __builtin_amdgcn_s_setprio(0);
    }

    #pragma unroll
    for (int mh = 0; mh < 2; ++mh)
      #pragma unroll
      for (int off = 1; off < 16; off <<= 1)
        #pragma unroll
        for (int r = 0; r < 4; ++r)
          rsum[mh][r] += __shfl_xor(rsum[mh][r], off);
    #pragma unroll
    for (int mh = 0; mh < 2; ++mh)
      #pragma unroll
      for (int r = 0; r < 4; ++r)
        l_run[mh][r] += rsum[mh][r];

    __syncthreads();
  }

  #pragma unroll
  for (int mh = 0; mh < 2; ++mh)
    #pragma unroll
    for (int ds = 0; ds < 8; ++ds)
      #pragma unroll
      for (int r = 0; r < 4; ++r) {
        const int q = q0 + mh * 16 + (lane >> 4) * 4 + r;
        const int d = ds * 16 + (lane & 15);
        ctx[((size_t)(b * S_ + q)) * H_ + h * HD_ + d] =
            (bf16_t)(acc[mh][ds][r] / l_run[mh][r]);
      }
}

// ---------------------------------------------------------------------- host
extern "C" void kernel_launch(void* const* d_in, const int* in_sizes, int n_in,
                              void* d_out, int out_size, void* d_ws, size_t ws_size,
                              hipStream_t stream) {
  (void)in_sizes; (void)n_in; (void)out_size; (void)ws_size;
  const float* x    = (const float*)d_in[0];
  const float* mask = (const float*)d_in[1];
  const float* Wq   = (const float*)d_in[2];
  const float* bq   = (const float*)d_in[3];
  const float* Wk   = (const float*)d_in[4];
  const float* bk   = (const float*)d_in[5];
  const float* Wv   = (const float*)d_in[6];
  const float* bv   = (const float*)d_in[7];
  const float* Wo   = (const float*)d_in[8];
  const float* bo   = (const float*)d_in[9];
  float* out = (float*)d_out;

  const size_t nX = (size_t)MM_ * H_;
  const size_t nW = (size_t)H_ * H_;

  bf16_t* xbf = (bf16_t*)d_ws;
  bf16_t* wqb = xbf + nX;
  bf16_t* wkb = wqb + nW;
  bf16_t* wvb = wkb + nW;
  bf16_t* wob = wvb + nW;
  bf16_t* qf  = wob + nW;   // frag-major Q
  bf16_t* kf  = qf + nX;    // frag-major K
  bf16_t* vf  = kf + nX;    // frag-major V
  bf16_t* cxb = vf + nX;

  cvt_f32_bf16<<<2048, 256, 0, stream>>>(x, xbf, (int)(nX / 8));
  cvt4_f32_bf16<<<dim3(1024, 4), 256, 0, stream>>>(Wq, Wk, Wv, Wo, wqb, wkb, wvb, wob, (int)(nW / 8));

  gemm8p<0><<<16 * 24, 512, 0, stream>>>(
      xbf, wqb, wkb, wvb, bq, bk, bv, qf, kf, vf, nullptr);

  attn_kernel<<<512, 256, 0, stream>>>(qf, kf, vf, mask, cxb);

  gemm8p<1><<<16 * 8, 512, 0, stream>>>(
      cxb, wob, nullptr, nullptr, bo, nullptr, nullptr, nullptr, nullptr, nullptr, out);
}